// Round 1
// 741.573 us; speedup vs baseline: 1.4290x; 1.4290x over previous
//
#include <hip/hip_runtime.h>
#include <hip/hip_bf16.h>
#include <climits>
#include <cstdint>

#define NB 65536   // batch
#define NP 1024    // prototypes
#define ND 512     // embed dim

// Hi-only f16 GEMM error (scaled units) has std ~4e-4; 4e-3 is ~7 sigma on the
// pairwise difference -> rows with approx top-2 gap below this get exact fp32
// recompute. Expected flagged rows ~1% of B (~600).
#define MARGIN 4e-3f

typedef _Float16 f16x8 __attribute__((ext_vector_type(8)));
typedef float    f32x4 __attribute__((ext_vector_type(4)));

__device__ inline void load_lds16(const void* g, void* l) {
    __builtin_amdgcn_global_load_lds(
        (const __attribute__((address_space(1))) void*)g,
        (__attribute__((address_space(3))) void*)l, 16, 0, 0);
}

// ---------------------------------------------------------------------------
// rnorm[p] = 1 / max(||c_p||, 1e-12). One wave per row.
// ---------------------------------------------------------------------------
__global__ void centroid_rnorm_kernel(const float* __restrict__ cent,
                                      float* __restrict__ rnorm) {
    const int row  = blockIdx.x * 4 + (threadIdx.x >> 6);
    const int lane = threadIdx.x & 63;
    const float4* cr = (const float4*)(cent + (size_t)row * ND);
    float4 a = cr[2 * lane];
    float4 b = cr[2 * lane + 1];
    float s = a.x * a.x + a.y * a.y + a.z * a.z + a.w * a.w
            + b.x * b.x + b.y * b.y + b.z * b.z + b.w * b.w;
#pragma unroll
    for (int off = 32; off > 0; off >>= 1)
        s += __shfl_down(s, off, 64);
    if (lane == 0)
        rnorm[row] = 1.0f / fmaxf(sqrtf(s), 1e-12f);
}

// ---------------------------------------------------------------------------
// fp32 -> f16 (hi only) converters.
// Qp layout: 65536 x 512 f16.   Cp layout: 1024 x 512 f16.
// ---------------------------------------------------------------------------
__global__ void convertQ_kernel(const float* __restrict__ Q,
                                _Float16* __restrict__ Qp) {
    const size_t t = (size_t)blockIdx.x * 256 + threadIdx.x;  // 8 elems/thread
    const size_t base = t * 8;
    const float4* s = (const float4*)(Q + base);
    float4 x0 = s[0], x1 = s[1];
    float xs[8] = {x0.x, x0.y, x0.z, x0.w, x1.x, x1.y, x1.z, x1.w};
    f16x8 hi;
#pragma unroll
    for (int i = 0; i < 8; ++i)
        hi[i] = (_Float16)xs[i];
    *(f16x8*)(Qp + base) = hi;
}

__global__ void convertC_kernel(const float* __restrict__ C,
                                _Float16* __restrict__ Cp) {
    const size_t t = (size_t)blockIdx.x * 256 + threadIdx.x;
    const size_t base = t * 8;
    const float4* s = (const float4*)(C + base);
    float4 x0 = s[0], x1 = s[1];
    float xs[8] = {x0.x, x0.y, x0.z, x0.w, x1.x, x1.y, x1.z, x1.w};
    f16x8 hi;
#pragma unroll
    for (int i = 0; i < 8; ++i)
        hi[i] = (_Float16)xs[i];
    *(f16x8*)(Cp + base) = hi;
}

// ---------------------------------------------------------------------------
// MFMA GEMM over K=512 (f16-hi only) fused with per-row top-2 tracking
// (scaled by rnorm). 128x128 block tile, 4 waves of 64x64 (4x4 MFMA 16x16x32
// f16), BK=64, global_load_lds width-16 staging.
// Grid 4096 = 512 m-blocks x 8 n-blocks, swizzled so the 8 n-blocks of an
// m-tile are consecutive on one XCD (A tile fetched once from HBM).
// Writes per (row, n-block): partial {v1, i1, v2}.
// ---------------------------------------------------------------------------
__launch_bounds__(256)
__global__ void gemm_top2_kernel(const _Float16* __restrict__ Qp,
                                 const _Float16* __restrict__ Cp,
                                 const float* __restrict__ rnorm,
                                 float* __restrict__ pv1,
                                 int*   __restrict__ pi1,
                                 float* __restrict__ pv2) {
    __shared__ __align__(16) _Float16 a_s[128 * 64];  // 16 KB
    __shared__ __align__(16) _Float16 b_s[128 * 64];  // 16 KB

    const int tid  = threadIdx.x;
    const int wave = tid >> 6, lane = tid & 63;

    // XCD-contiguous swizzle: xcd = bid&7 sees all 8 n for each of its m's.
    const int bid = blockIdx.x;
    const int x = bid & 7, j = bid >> 3;
    const int nb = j & 7;
    const int mb = (j >> 3) * 8 + x;
    const int mbase = mb * 128, nbase = nb * 128;

    const int wm = wave >> 1, wn = wave & 1;
    const int quad = lane >> 4, l15 = lane & 15;

    f32x4 acc[4][4] = {};

    // staging addressing: lane l covers row (seg*8 + l>>3), col (l&7)*8
    const _Float16* aBase = Qp + (size_t)(mbase + (lane >> 3)) * 512 + ((lane & 7) << 3);
    const _Float16* bBase = Cp + (size_t)(nbase + (lane >> 3)) * 512 + ((lane & 7) << 3);
    _Float16* aDst = a_s + wave * 512;
    _Float16* bDst = b_s + wave * 512;

    for (int kc = 0; kc < 8; ++kc) {
        const int kv = kc << 6;
        __syncthreads();
#pragma unroll
        for (int it = 0; it < 4; ++it) {
            const int s8 = (it * 4 + wave) * 8;
            load_lds16(aBase + (size_t)s8 * 512 + kv, aDst + it * 2048);
            load_lds16(bBase + (size_t)s8 * 512 + kv, bDst + it * 2048);
        }
        __syncthreads();
#pragma unroll
        for (int kk = 0; kk < 64; kk += 32) {
            f16x8 af[4], bf[4];
#pragma unroll
            for (int mt = 0; mt < 4; ++mt)
                af[mt] = *(const f16x8*)&a_s[(wm * 64 + mt * 16 + l15) * 64 + kk + quad * 8];
#pragma unroll
            for (int nt = 0; nt < 4; ++nt)
                bf[nt] = *(const f16x8*)&b_s[(wn * 64 + nt * 16 + l15) * 64 + kk + quad * 8];
#pragma unroll
            for (int mt = 0; mt < 4; ++mt)
#pragma unroll
                for (int nt = 0; nt < 4; ++nt)
                    acc[mt][nt] = __builtin_amdgcn_mfma_f32_16x16x32_f16(
                        af[mt], bf[nt], acc[mt][nt], 0, 0, 0);
        }
    }

    // ---- epilogue: scale + per-row top-2 over this block's 128 cols ----
    __syncthreads();
    float* lv1 = (float*)a_s;          // [128][2]
    int*   li1 = (int*)(lv1 + 256);    // [128][2]
    float* lv2 = (float*)(li1 + 256);  // [128][2]

    float rn[4];
#pragma unroll
    for (int nt = 0; nt < 4; ++nt)
        rn[nt] = rnorm[nbase + wn * 64 + nt * 16 + l15];

#pragma unroll
    for (int mt = 0; mt < 4; ++mt) {
#pragma unroll
        for (int r = 0; r < 4; ++r) {
            float v1 = -3.0e38f, v2 = -3.0e38f; int i1 = INT_MAX;
#pragma unroll
            for (int nt = 0; nt < 4; ++nt) {
                float v = acc[mt][nt][r] * rn[nt];
                int   c = nbase + wn * 64 + nt * 16 + l15;
                if (v > v1) { v2 = v1; v1 = v; i1 = c; }
                else { if (v > v2) v2 = v; if (v == v1 && c < i1) i1 = c; }
            }
            // butterfly over the 16 column-lanes (same rows)
#pragma unroll
            for (int mask = 1; mask < 16; mask <<= 1) {
                float ov1 = __shfl_xor(v1, mask, 64);
                int   oi1 = __shfl_xor(i1, mask, 64);
                float ov2 = __shfl_xor(v2, mask, 64);
                if (ov1 > v1) { v2 = fmaxf(v1, ov2); v1 = ov1; i1 = oi1; }
                else if (ov1 == v1) { v2 = v1; i1 = min(i1, oi1); }
                else { v2 = fmaxf(v2, ov1); }
            }
            if (l15 == 0) {
                int row = wm * 64 + mt * 16 + quad * 4 + r;
                lv1[row * 2 + wn] = v1;
                li1[row * 2 + wn] = i1;
                lv2[row * 2 + wn] = v2;
            }
        }
    }
    __syncthreads();
    if (tid < 128) {
        float v1 = lv1[tid * 2],     v2 = lv2[tid * 2];     int i1 = li1[tid * 2];
        float w1 = lv1[tid * 2 + 1], w2 = lv2[tid * 2 + 1]; int j1 = li1[tid * 2 + 1];
        float V1, V2; int I1;
        if (w1 > v1)       { V1 = w1; I1 = j1; V2 = fmaxf(v1, w2); }
        else if (w1 == v1) { V1 = v1; I1 = min(i1, j1); V2 = v1; }
        else               { V1 = v1; I1 = i1; V2 = fmaxf(v2, w1); }
        const size_t g = (size_t)(mbase + tid) * 8 + nb;
        pv1[g] = V1; pi1[g] = I1; pv2[g] = V2;
    }
}

// ---------------------------------------------------------------------------
// Merge the 8 per-chunk partials per row; write argmax; flag near-ties.
// ---------------------------------------------------------------------------
__global__ void merge_kernel(const float* __restrict__ pv1,
                             const int*   __restrict__ pi1,
                             const float* __restrict__ pv2,
                             float* __restrict__ assign_out,
                             int* __restrict__ rlist, int* __restrict__ rcount) {
    const int row = blockIdx.x * 256 + threadIdx.x;
    float v1 = -3.0e38f, v2 = -3.0e38f; int i1 = INT_MAX;
    const size_t b = (size_t)row * 8;
#pragma unroll
    for (int n = 0; n < 8; ++n) {
        float a1 = pv1[b + n]; int ai = pi1[b + n]; float a2 = pv2[b + n];
        if (a1 > v1)       { v2 = fmaxf(v1, a2); v1 = a1; i1 = ai; }
        else if (a1 == v1) { v2 = v1; i1 = min(i1, ai); }
        else               { v2 = fmaxf(v2, a1); }
    }
    assign_out[row] = (float)i1;
    if (v1 - v2 < MARGIN) {
        int p = atomicAdd(rcount, 1);
        rlist[p] = row;
    }
}

// ---------------------------------------------------------------------------
// Exact fp32 recompute for flagged rows (full 1024 centroids per row).
// Restructured for ~1% flagged rows: grid 512, 2 rows per block (each
// centroid row read once serves both), 4 protos in flight per wave iteration
// (independent loads + interleaved reduce trees -> ILP hides L2 latency).
// ---------------------------------------------------------------------------
__launch_bounds__(256)
__global__ void refine_kernel(const float* __restrict__ Q,
                              const float* __restrict__ C,
                              const float* __restrict__ rnorm,
                              const int* __restrict__ rlist,
                              const int* __restrict__ rcount,
                              float* __restrict__ assign_out) {
    __shared__ float wv[8];
    __shared__ int   wi[8];
    const int n = *rcount;
    const int wave = threadIdx.x >> 6, lane = threadIdx.x & 63;
    for (int it = blockIdx.x * 2; it < n; it += gridDim.x * 2) {
        const int rowA = rlist[it];
        const int rowB = rlist[(it + 1 < n) ? (it + 1) : it];  // dup ok (same value write)
        const float4* qrA = (const float4*)(Q + (size_t)rowA * ND);
        const float4* qrB = (const float4*)(Q + (size_t)rowB * ND);
        float4 qa  = qrA[lane], qa2 = qrA[lane + 64];
        float4 qb  = qrB[lane], qb2 = qrB[lane + 64];
        float bestA = -3.0e38f, bestB = -3.0e38f;
        int   biA = INT_MAX,    biB = INT_MAX;
        for (int i = 0; i < 64; ++i) {
            const int p0 = i * 16 + wave * 4;   // ascending p within each wave
            float sA[4], sB[4];
#pragma unroll
            for (int jj = 0; jj < 4; ++jj) {
                const float4* cr = (const float4*)(C + (size_t)(p0 + jj) * ND);
                float4 b = cr[lane], b2 = cr[lane + 64];
                sA[jj] = qa.x * b.x + qa.y * b.y + qa.z * b.z + qa.w * b.w
                       + qa2.x * b2.x + qa2.y * b2.y + qa2.z * b2.z + qa2.w * b2.w;
                sB[jj] = qb.x * b.x + qb.y * b.y + qb.z * b.z + qb.w * b.w
                       + qb2.x * b2.x + qb2.y * b2.y + qb2.z * b2.z + qb2.w * b2.w;
            }
#pragma unroll
            for (int m = 1; m < 64; m <<= 1) {
#pragma unroll
                for (int jj = 0; jj < 4; ++jj) {
                    sA[jj] += __shfl_xor(sA[jj], m, 64);
                    sB[jj] += __shfl_xor(sB[jj], m, 64);
                }
            }
#pragma unroll
            for (int jj = 0; jj < 4; ++jj) {
                float rnv = rnorm[p0 + jj];
                float vA = sA[jj] * rnv, vB = sB[jj] * rnv;
                if (vA > bestA) { bestA = vA; biA = p0 + jj; }  // first-max wins
                if (vB > bestB) { bestB = vB; biB = p0 + jj; }
            }
        }
        __syncthreads();  // protect wv/wi reuse across row iterations
        if (lane == 0) {
            wv[wave] = bestA;     wi[wave] = biA;
            wv[4 + wave] = bestB; wi[4 + wave] = biB;
        }
        __syncthreads();
        if (threadIdx.x == 0) {
            float bv = wv[0]; int b0 = wi[0];
            for (int w = 1; w < 4; ++w)
                if (wv[w] > bv || (wv[w] == bv && wi[w] < b0)) { bv = wv[w]; b0 = wi[w]; }
            assign_out[rowA] = (float)b0;
        }
        if (threadIdx.x == 64) {
            float bv = wv[4]; int b0 = wi[4];
            for (int w = 5; w < 8; ++w)
                if (wv[w] > bv || (wv[w] == bv && wi[w] < b0)) { bv = wv[w]; b0 = wi[w]; }
            assign_out[rowB] = (float)b0;
        }
    }
}

// ---------------------------------------------------------------------------
// ctx gather + routing row write (zeros fused with the single 1.0).
// Covers the entire routing region, so no separate memset is needed.
// ---------------------------------------------------------------------------
__global__ void scatter_kernel(const float* __restrict__ cent,
                               const float* __restrict__ assign,
                               float* __restrict__ ctx,
                               float* __restrict__ routing) {
    const int q    = blockIdx.x * 2 + (threadIdx.x >> 7);
    const int lane = threadIdx.x & 127;
    const int ci   = (int)assign[q];
    const float4* src = (const float4*)(cent + (size_t)ci * ND);
    ((float4*)(ctx + (size_t)q * ND))[lane] = src[lane];
    float4 z1 = {0.f, 0.f, 0.f, 0.f};
    float4 z2 = {0.f, 0.f, 0.f, 0.f};
    if ((ci >> 2) == lane)        ((float*)&z1)[ci & 3] = 1.0f;
    if ((ci >> 2) == lane + 128)  ((float*)&z2)[ci & 3] = 1.0f;
    float4* rr = (float4*)(routing + (size_t)q * NP);
    rr[lane]       = z1;
    rr[lane + 128] = z2;
}

// ---------------------------------------------------------------------------
extern "C" void kernel_launch(void* const* d_in, const int* in_sizes, int n_in,
                              void* d_out, int out_size, void* d_ws, size_t ws_size,
                              hipStream_t stream) {
    const float* query = (const float*)d_in[0];   // (B, D) fp32
    const float* cent  = (const float*)d_in[1];   // (P, D) fp32

    float* out        = (float*)d_out;
    float* ctx        = out;                       // B*D
    float* assign_out = out + (size_t)NB * ND;     // B
    float* routing    = assign_out + NB;           // B*P (268 MB)

    // All bulky scratch lives inside the routing region; it is fully
    // overwritten by scatter_kernel at the end. d_ws is unused.
    char* scratch = (char*)routing;
    _Float16* Qp    = (_Float16*)(scratch);                       // 67,108,864 B
    _Float16* Cp    = (_Float16*)(scratch + 67108864);            //  1,048,576 B
    float*    rnorm = (float*)   (scratch + 68157440);            //      4,096 B
    float*    pv1   = (float*)   (scratch + 68161536);            //  2,097,152 B
    int*      pi1   = (int*)     (scratch + 70258688);            //  2,097,152 B
    float*    pv2   = (float*)   (scratch + 72355840);            //  2,097,152 B
    int*      rlist = (int*)     (scratch + 74452992);            //    262,144 B
    int*      rcount= (int*)     (scratch + 74715136);            //          4 B

    hipMemsetAsync(rcount, 0, sizeof(int), stream);

    centroid_rnorm_kernel<<<NP / 4, 256, 0, stream>>>(cent, rnorm);
    convertC_kernel<<<NP * ND / 8 / 256, 256, 0, stream>>>(cent, Cp);
    convertQ_kernel<<<NB * (ND / 8) / 256, 256, 0, stream>>>(query, Qp);
    gemm_top2_kernel<<<4096, 256, 0, stream>>>(Qp, Cp, rnorm, pv1, pi1, pv2);
    merge_kernel<<<NB / 256, 256, 0, stream>>>(pv1, pi1, pv2, assign_out, rlist, rcount);
    refine_kernel<<<512, 256, 0, stream>>>(query, cent, rnorm, rlist, rcount, assign_out);
    scatter_kernel<<<NB / 2, 256, 0, stream>>>(cent, assign_out, ctx, routing);
}